// Round 2
// baseline (440.435 us; speedup 1.0000x reference)
//
#include <hip/hip_runtime.h>
#include <stdint.h>

typedef __bf16          bf16x8  __attribute__((ext_vector_type(8)));
typedef unsigned short  ushort8 __attribute__((ext_vector_type(8)));
typedef float           f32x4   __attribute__((ext_vector_type(4)));
typedef int             i32x4   __attribute__((ext_vector_type(4)));

__device__ __forceinline__ unsigned short f2bf(float f) {
    unsigned int u = __float_as_uint(f);
    return (unsigned short)((u + 0x7FFFu + ((u >> 16) & 1u)) >> 16);
}

#define W1_SLOTS (12*16*64)
#define W2_SLOTS (8*16*64)

// Repack weights fp32 -> bf16 MFMA A-operand fragments (for the swapped scheme
// D = W^T · h^T).  Slot (s,t,l), elements j=0..7, lane quad lq = l>>4:
//   w1f: element j = w1[k = s*32 + lq*8 + j][n = t*16 + (l&15)]
//        (A-frag of W1^T: A[arow=l15 -> n][k' = lq*8+j -> k])
//   w2f: element j = w2[f][n],  f = s*32 + lq*4 + (j&3) + (j>>2)*16
//        k-order of layer 2 is REDEFINED so that the h1 registers produced by
//        layer 1's C-layout (lane holds features t*16+lq*4+{0..3}) drop into
//        B-fragment slots with no cross-lane shuffle: k' = lq*8 + j of step s
//        carries feature f above; (s,j>>1) -> (tile 2s+(j>>2), pair (j>>1)&1)
//        is a bijection over all 256 features.
__global__ void prep_weights(const float* __restrict__ w1, const float* __restrict__ w2,
                             unsigned short* __restrict__ w1f, unsigned short* __restrict__ w2f) {
    int id = blockIdx.x * 256 + threadIdx.x;
    if (id < W1_SLOTS) {
        int slot = id;
        int l  = slot & 63;
        int t  = (slot >> 6) & 15;
        int s  = slot >> 10;
        int k0 = s*32 + ((l >> 4) << 3);
        int n  = t*16 + (l & 15);
        unsigned short* d = w1f + (size_t)slot * 8;
        #pragma unroll
        for (int j = 0; j < 8; ++j) d[j] = f2bf(w1[(size_t)(k0 + j) * 256 + n]);
    } else if (id < W1_SLOTS + W2_SLOTS) {
        int slot = id - W1_SLOTS;
        int l  = slot & 63;
        int t  = (slot >> 6) & 15;
        int s  = slot >> 10;
        int fb = s*32 + ((l >> 4) << 2);       // s*32 + lq*4
        int n  = t*16 + (l & 15);
        unsigned short* d = w2f + (size_t)slot * 8;
        #pragma unroll
        for (int j = 0; j < 8; ++j) {
            int f = fb + (j & 3) + ((j >> 2) << 4);
            d[j] = f2bf(w2[(size_t)f * 256 + n]);
        }
    }
}

// Swapped-operand scheme: compute out^T tiles D = (W^T)·(h^T).
// C-layout: col(l15) = batch row, row(lq*4+reg) = feature.
// h1 never leaves registers; layer-2 shuffle absorbed into w2 repack.
// No LDS, no __syncthreads, vectorized f32x4 output stores.
__global__ __launch_bounds__(256, 2) void courier_main(
    const float* __restrict__ xy,   const float* __restrict__ tin,
    const float* __restrict__ w_sx, const float* __restrict__ b_sx,
    const float* __restrict__ w_cx, const float* __restrict__ b_cx,
    const float* __restrict__ w_sy, const float* __restrict__ b_sy,
    const float* __restrict__ w_cy, const float* __restrict__ b_cy,
    const float* __restrict__ w_t,  const float* __restrict__ b_t,
    const unsigned short* __restrict__ w1f, const float* __restrict__ b1,
    const unsigned short* __restrict__ w2f, const float* __restrict__ b2,
    float* __restrict__ out)
{
    const int tid  = threadIdx.x;
    const int lane = tid & 63;
    const int wv   = tid >> 6;     // wave 0..3; wave covers rows [wv*32, wv*32+32)
    const int l15  = lane & 15;
    const int lq   = lane >> 4;    // quad 0..3
    const int rowblk = blockIdx.x * 128;

    // per-lane batch rows for the two N-tiles (row = wv*32 + m*16 + l15)
    const int r0 = wv*32 + l15;
    const int r1 = r0 + 16;
    const float x0 = xy[(size_t)(rowblk + r0)*2 + 0];
    const float y0 = xy[(size_t)(rowblk + r0)*2 + 1];
    const float t0 = tin[rowblk + r0];
    const float x1 = xy[(size_t)(rowblk + r1)*2 + 0];
    const float y1 = xy[(size_t)(rowblk + r1)*2 + 1];
    const float t1 = tin[rowblk + r1];

    f32x4 acc[2][16];
    #pragma unroll
    for (int m=0;m<2;++m)
      #pragma unroll
      for (int n=0;n<16;++n)
        #pragma unroll
        for (int i=0;i<4;++i) acc[m][n][i] = 0.0f;

    // ---------------- layer 1: acc[m][t] = (w1^T tile t)·(h^T tile m) -----------
    for (int s = 0; s < 12; ++s) {
        // weight A-frags straight from global (L1/L2-resident, uniform addresses)
        const bf16x8* gsrc = (const bf16x8*)w1f + (size_t)(s*16*64) + lane;
        bf16x8 wfr[16];
        #pragma unroll
        for (int t = 0; t < 16; ++t) wfr[t] = gsrc[t*64];

        // embedding B-frags: lane holds h[row=base+m*16+l15][k = s*32 + lq*8 + j]
        // (long VALU block — covers the global-load latency above)
        ushort8 u0, u1;
        if (s < 8) {                           // sin/cos segments
            const int seg = s >> 1;            // 0:sinx 1:cosx 2:siny 3:cosy
            const float* wp = (seg==0)?w_sx:(seg==1)?w_cx:(seg==2)?w_sy:w_cy;
            const float* bp = (seg==0)?b_sx:(seg==1)?b_cx:(seg==2)?b_sy:b_cy;
            const float c0 = (seg<2)?x0:y0;
            const float c1 = (seg<2)?x1:y1;
            const int o = ((s & 1) << 5) + lq*8;
            f32x4 wa = *(const f32x4*)(wp+o), wb = *(const f32x4*)(wp+o+4);
            f32x4 ba = *(const f32x4*)(bp+o), bb = *(const f32x4*)(bp+o+4);
            #pragma unroll
            for (int j=0;j<8;++j) {
                float wvv = (j<4)?wa[j]:wb[j-4];
                float bvv = (j<4)?ba[j]:bb[j-4];
                float th0 = c0*wvv + bvv;
                float th1 = c1*wvv + bvv;
                float v0, v1;
                if ((s & 2) == 0) { v0 = __sinf(th0); v1 = __sinf(th1); }
                else              { v0 = __cosf(th0); v1 = __cosf(th1); }
                u0[j] = f2bf(v0); u1[j] = f2bf(v1);
            }
        } else {                               // time embedding, k in [256,384)
            const int o = (s-8)*32 + lq*8;
            f32x4 wa = *(const f32x4*)(w_t+o), wb = *(const f32x4*)(w_t+o+4);
            f32x4 ba = *(const f32x4*)(b_t+o), bb = *(const f32x4*)(b_t+o+4);
            #pragma unroll
            for (int j=0;j<8;++j) {
                float wvv = (j<4)?wa[j]:wb[j-4];
                float bvv = (j<4)?ba[j]:bb[j-4];
                float th0 = t0*wvv + bvv;
                float th1 = t1*wvv + bvv;
                u0[j] = f2bf(fmaxf(th0, 0.01f*th0));
                u1[j] = f2bf(fmaxf(th1, 0.01f*th1));
            }
        }
        bf16x8 e0 = __builtin_bit_cast(bf16x8, u0);
        bf16x8 e1 = __builtin_bit_cast(bf16x8, u1);

        #pragma unroll
        for (int t = 0; t < 16; ++t) {
            acc[0][t] = __builtin_amdgcn_mfma_f32_16x16x32_bf16(wfr[t], e0, acc[0][t], 0,0,0);
            acc[1][t] = __builtin_amdgcn_mfma_f32_16x16x32_bf16(wfr[t], e1, acc[1][t], 0,0,0);
        }
    }

    // ---------------- epilogue 1: h1 bias+leaky -> packed bf16 pairs in VGPRs ----
    // lane holds h1[row=base+m*16+l15][feature = t*16 + lq*4 + reg]
    // pk[m][t][p] = bf16 pair (features t*16+lq*4+2p low, +2p+1 high)
    int pk[2][16][2];
    #pragma unroll
    for (int t=0;t<16;++t) {
        const f32x4 bv = *(const f32x4*)(b1 + t*16 + lq*4);
        #pragma unroll
        for (int m=0;m<2;++m) {
            float v0 = acc[m][t][0] + bv[0]; v0 = fmaxf(v0, 0.01f*v0);
            float v1 = acc[m][t][1] + bv[1]; v1 = fmaxf(v1, 0.01f*v1);
            float v2 = acc[m][t][2] + bv[2]; v2 = fmaxf(v2, 0.01f*v2);
            float v3 = acc[m][t][3] + bv[3]; v3 = fmaxf(v3, 0.01f*v3);
            pk[m][t][0] = ((int)f2bf(v1) << 16) | (int)f2bf(v0);
            pk[m][t][1] = ((int)f2bf(v3) << 16) | (int)f2bf(v2);
        }
    }

    #pragma unroll
    for (int m=0;m<2;++m)
      #pragma unroll
      for (int n=0;n<16;++n)
        #pragma unroll
        for (int i=0;i<4;++i) acc[m][n][i] = 0.0f;

    // ---------------- layer 2: B-frags are the lane's own pk registers ----------
    // k' = lq*8 + j of step s carries feature f = s*32 + lq*4 + (j&3) + (j>>2)*16
    // (matching w2f repack) -> dword i of B-frag = pk[m][2s + (i>>1)][i&1].
    #pragma unroll
    for (int s = 0; s < 8; ++s) {
        const bf16x8* gsrc = (const bf16x8*)w2f + (size_t)(s*16*64) + lane;
        bf16x8 wfr[8];
        #pragma unroll
        for (int t = 0; t < 8; ++t) wfr[t] = gsrc[t*64];

        i32x4 f0, f1;
        f0[0] = pk[0][2*s  ][0];  f0[1] = pk[0][2*s  ][1];
        f0[2] = pk[0][2*s+1][0];  f0[3] = pk[0][2*s+1][1];
        f1[0] = pk[1][2*s  ][0];  f1[1] = pk[1][2*s  ][1];
        f1[2] = pk[1][2*s+1][0];  f1[3] = pk[1][2*s+1][1];
        bf16x8 e0 = __builtin_bit_cast(bf16x8, f0);
        bf16x8 e1 = __builtin_bit_cast(bf16x8, f1);

        #pragma unroll
        for (int t = 0; t < 8; ++t) {
            acc[0][t] = __builtin_amdgcn_mfma_f32_16x16x32_bf16(wfr[t], e0, acc[0][t], 0,0,0);
            acc[1][t] = __builtin_amdgcn_mfma_f32_16x16x32_bf16(wfr[t], e1, acc[1][t], 0,0,0);
        }
        #pragma unroll
        for (int t = 0; t < 8; ++t) wfr[t] = gsrc[(8+t)*64];
        #pragma unroll
        for (int t = 0; t < 8; ++t) {
            acc[0][8+t] = __builtin_amdgcn_mfma_f32_16x16x32_bf16(wfr[t], e0, acc[0][8+t], 0,0,0);
            acc[1][8+t] = __builtin_amdgcn_mfma_f32_16x16x32_bf16(wfr[t], e1, acc[1][8+t], 0,0,0);
        }
    }

    // ---------------- epilogue 2: out = leaky(acc+b2), vectorized f32x4 stores ---
    #pragma unroll
    for (int t=0;t<16;++t) {
        const f32x4 bv = *(const f32x4*)(b2 + t*16 + lq*4);
        #pragma unroll
        for (int m=0;m<2;++m) {
            f32x4 o;
            #pragma unroll
            for (int r=0;r<4;++r) {
                float v = acc[m][t][r] + bv[r];
                o[r] = fmaxf(v, 0.01f*v);
            }
            const int row = rowblk + wv*32 + m*16 + l15;
            *(f32x4*)(out + (size_t)row*256 + t*16 + lq*4) = o;
        }
    }
}

extern "C" void kernel_launch(void* const* d_in, const int* in_sizes, int n_in,
                              void* d_out, int out_size, void* d_ws, size_t ws_size,
                              hipStream_t stream) {
    const float* xy   = (const float*)d_in[0];
    const float* tin  = (const float*)d_in[1];
    const float* w_sx = (const float*)d_in[2];
    const float* b_sx = (const float*)d_in[3];
    const float* w_cx = (const float*)d_in[4];
    const float* b_cx = (const float*)d_in[5];
    const float* w_sy = (const float*)d_in[6];
    const float* b_sy = (const float*)d_in[7];
    const float* w_cy = (const float*)d_in[8];
    const float* b_cy = (const float*)d_in[9];
    const float* w_t  = (const float*)d_in[10];
    const float* b_t  = (const float*)d_in[11];
    const float* w1   = (const float*)d_in[12];
    const float* b1   = (const float*)d_in[13];
    const float* w2   = (const float*)d_in[14];
    const float* b2   = (const float*)d_in[15];

    unsigned short* w1f = (unsigned short*)d_ws;        // 12*16*64*8 ushorts = 196608 B
    unsigned short* w2f = w1f + (size_t)W1_SLOTS * 8;   // 131072 B

    prep_weights<<<(W1_SLOTS + W2_SLOTS + 255)/256, 256, 0, stream>>>(w1, w2, w1f, w2f);
    courier_main<<<262144/128, 256, 0, stream>>>(xy, tin, w_sx,b_sx,w_cx,b_cx,
                                                 w_sy,b_sy,w_cy,b_cy,w_t,b_t,
                                                 w1f, b1, w2f, b2, (float*)d_out);
}

// Round 3
// 418.022 us; speedup vs baseline: 1.0536x; 1.0536x over previous
//
#include <hip/hip_runtime.h>
#include <stdint.h>

typedef __bf16          bf16x8  __attribute__((ext_vector_type(8)));
typedef unsigned short  ushort8 __attribute__((ext_vector_type(8)));
typedef float           f32x4   __attribute__((ext_vector_type(4)));
typedef int             i32x4   __attribute__((ext_vector_type(4)));

__device__ __forceinline__ unsigned short f2bf(float f) {
    unsigned int u = __float_as_uint(f);
    return (unsigned short)((u + 0x7FFFu + ((u >> 16) & 1u)) >> 16);
}

#define W1_SLOTS (12*16*64)
#define W2_SLOTS (8*16*64)

// Repack weights fp32 -> bf16 MFMA A-operand fragments (swapped scheme
// D = W^T · h^T).  Slot (s,t,l), elements j=0..7, lane quad lq = l>>4:
//   w1f: element j = w1[k = s*32 + lq*8 + j][n = t*16 + (l&15)]
//   w2f: element j = w2[f][n],  f = s*32 + lq*4 + (j&3) + (j>>2)*16
//        (layer-2 k-order chosen so layer-1's register-resident h1 drops into
//        B-fragment slots with no cross-lane shuffle; validated in round 2)
__global__ void prep_weights(const float* __restrict__ w1, const float* __restrict__ w2,
                             unsigned short* __restrict__ w1f, unsigned short* __restrict__ w2f) {
    int id = blockIdx.x * 256 + threadIdx.x;
    if (id < W1_SLOTS) {
        int slot = id;
        int l  = slot & 63;
        int t  = (slot >> 6) & 15;
        int s  = slot >> 10;
        int k0 = s*32 + ((l >> 4) << 3);
        int n  = t*16 + (l & 15);
        unsigned short* d = w1f + (size_t)slot * 8;
        #pragma unroll
        for (int j = 0; j < 8; ++j) d[j] = f2bf(w1[(size_t)(k0 + j) * 256 + n]);
    } else if (id < W1_SLOTS + W2_SLOTS) {
        int slot = id - W1_SLOTS;
        int l  = slot & 63;
        int t  = (slot >> 6) & 15;
        int s  = slot >> 10;
        int fb = s*32 + ((l >> 4) << 2);       // s*32 + lq*4
        int n  = t*16 + (l & 15);
        unsigned short* d = w2f + (size_t)slot * 8;
        #pragma unroll
        for (int j = 0; j < 8; ++j) {
            int f = fb + (j & 3) + ((j >> 2) << 4);
            d[j] = f2bf(w2[(size_t)f * 256 + n]);
        }
    }
}

// Swapped-operand scheme (validated): C col(l15)=batch row, C row(lq*4+reg)=feature.
// h1 stays in registers; weights staged to LDS once per BLOCK (amortized over 4
// waves — the round-2 version's per-wave L2 streams were the 208 µs bottleneck),
// double-buffered with ONE barrier per k-step; loads issued early, ds_write late.
__global__ __launch_bounds__(256, 2) void courier_main(
    const float* __restrict__ xy,   const float* __restrict__ tin,
    const float* __restrict__ w_sx, const float* __restrict__ b_sx,
    const float* __restrict__ w_cx, const float* __restrict__ b_cx,
    const float* __restrict__ w_sy, const float* __restrict__ b_sy,
    const float* __restrict__ w_cy, const float* __restrict__ b_cy,
    const float* __restrict__ w_t,  const float* __restrict__ b_t,
    const unsigned short* __restrict__ w1f, const float* __restrict__ b1,
    const unsigned short* __restrict__ w2f, const float* __restrict__ b2,
    float* __restrict__ out)
{
    __shared__ __align__(16) unsigned short stage[2][8192];   // 2 x 16 KB ping-pong

    const int tid  = threadIdx.x;
    const int lane = tid & 63;
    const int wv   = tid >> 6;     // wave 0..3; wave covers rows [wv*32, wv*32+32)
    const int l15  = lane & 15;
    const int lq   = lane >> 4;    // quad 0..3
    const int rowblk = blockIdx.x * 128;

    const int r0 = wv*32 + l15;
    const int r1 = r0 + 16;
    const float x0 = xy[(size_t)(rowblk + r0)*2 + 0];
    const float y0 = xy[(size_t)(rowblk + r0)*2 + 1];
    const float t0 = tin[rowblk + r0];
    const float x1 = xy[(size_t)(rowblk + r1)*2 + 0];
    const float y1 = xy[(size_t)(rowblk + r1)*2 + 1];
    const float t1 = tin[rowblk + r1];

    // chunk c (16 KB of fragment data): c<12 -> w1f, else w2f
    auto chunkptr = [&](int c) -> const bf16x8* {
        return (c < 12) ? (const bf16x8*)(w1f + (size_t)c * 8192)
                        : (const bf16x8*)(w2f + (size_t)(c - 12) * 8192);
    };

    f32x4 acc[2][16];
    #pragma unroll
    for (int m=0;m<2;++m)
      #pragma unroll
      for (int n=0;n<16;++n)
        #pragma unroll
        for (int i=0;i<4;++i) acc[m][n][i] = 0.0f;

    // prologue: stage chunk 0 into buf 0
    {
        const bf16x8* g = chunkptr(0);
        bf16x8* sd = (bf16x8*)stage[0];
        bf16x8 st[4];
        #pragma unroll
        for (int i=0;i<4;++i) st[i] = g[i*256 + tid];
        #pragma unroll
        for (int i=0;i<4;++i) sd[i*256 + tid] = st[i];
        __syncthreads();
    }

    // ---------------- layer 1: acc[m][t] = (w1^T tile t)·(h^T tile m) -----------
    for (int s = 0; s < 12; ++s) {
        const int buf = s & 1;

        // issue next-chunk loads EARLY (latency hides under this whole step)
        const bf16x8* gn = chunkptr(s + 1);
        bf16x8 stg[4];
        #pragma unroll
        for (int i=0;i<4;++i) stg[i] = gn[i*256 + tid];

        // embedding B-frags: lane holds h[row=base+m*16+l15][k = s*32 + lq*8 + j]
        ushort8 u0, u1;
        if (s < 8) {                           // sin/cos segments
            const int seg = s >> 1;            // 0:sinx 1:cosx 2:siny 3:cosy
            const float* wp = (seg==0)?w_sx:(seg==1)?w_cx:(seg==2)?w_sy:w_cy;
            const float* bp = (seg==0)?b_sx:(seg==1)?b_cx:(seg==2)?b_sy:b_cy;
            const float c0 = (seg<2)?x0:y0;
            const float c1 = (seg<2)?x1:y1;
            const int o = ((s & 1) << 5) + lq*8;
            f32x4 wa = *(const f32x4*)(wp+o), wb = *(const f32x4*)(wp+o+4);
            f32x4 ba = *(const f32x4*)(bp+o), bb = *(const f32x4*)(bp+o+4);
            #pragma unroll
            for (int j=0;j<8;++j) {
                float wvv = (j<4)?wa[j]:wb[j-4];
                float bvv = (j<4)?ba[j]:bb[j-4];
                float th0 = c0*wvv + bvv;
                float th1 = c1*wvv + bvv;
                float v0, v1;
                if ((s & 2) == 0) { v0 = __sinf(th0); v1 = __sinf(th1); }
                else              { v0 = __cosf(th0); v1 = __cosf(th1); }
                u0[j] = f2bf(v0); u1[j] = f2bf(v1);
            }
        } else {                               // time embedding, k in [256,384)
            const int o = (s-8)*32 + lq*8;
            f32x4 wa = *(const f32x4*)(w_t+o), wb = *(const f32x4*)(w_t+o+4);
            f32x4 ba = *(const f32x4*)(b_t+o), bb = *(const f32x4*)(b_t+o+4);
            #pragma unroll
            for (int j=0;j<8;++j) {
                float wvv = (j<4)?wa[j]:wb[j-4];
                float bvv = (j<4)?ba[j]:bb[j-4];
                float th0 = t0*wvv + bvv;
                float th1 = t1*wvv + bvv;
                u0[j] = f2bf(fmaxf(th0, 0.01f*th0));
                u1[j] = f2bf(fmaxf(th1, 0.01f*th1));
            }
        }
        bf16x8 e0 = __builtin_bit_cast(bf16x8, u0);
        bf16x8 e1 = __builtin_bit_cast(bf16x8, u1);

        // ds_read current chunk's fragments + MFMA (no dependency on stg loads)
        const bf16x8* sb = (const bf16x8*)stage[buf];
        #pragma unroll
        for (int t = 0; t < 16; ++t) {
            bf16x8 w = sb[t*64 + lane];
            acc[0][t] = __builtin_amdgcn_mfma_f32_16x16x32_bf16(w, e0, acc[0][t], 0,0,0);
            acc[1][t] = __builtin_amdgcn_mfma_f32_16x16x32_bf16(w, e1, acc[1][t], 0,0,0);
        }

        // write-late: stage next chunk, then the step's single barrier
        bf16x8* sd = (bf16x8*)stage[buf ^ 1];
        #pragma unroll
        for (int i=0;i<4;++i) sd[i*256 + tid] = stg[i];
        __syncthreads();
    }

    // ---------------- epilogue 1: h1 bias+leaky -> packed bf16 pairs in VGPRs ----
    int pk[2][16][2];
    #pragma unroll
    for (int t=0;t<16;++t) {
        const f32x4 bv = *(const f32x4*)(b1 + t*16 + lq*4);
        #pragma unroll
        for (int m=0;m<2;++m) {
            float v0 = acc[m][t][0] + bv[0]; v0 = fmaxf(v0, 0.01f*v0);
            float v1 = acc[m][t][1] + bv[1]; v1 = fmaxf(v1, 0.01f*v1);
            float v2 = acc[m][t][2] + bv[2]; v2 = fmaxf(v2, 0.01f*v2);
            float v3 = acc[m][t][3] + bv[3]; v3 = fmaxf(v3, 0.01f*v3);
            pk[m][t][0] = ((int)f2bf(v1) << 16) | (int)f2bf(v0);
            pk[m][t][1] = ((int)f2bf(v3) << 16) | (int)f2bf(v2);
        }
    }

    #pragma unroll
    for (int m=0;m<2;++m)
      #pragma unroll
      for (int n=0;n<16;++n)
        #pragma unroll
        for (int i=0;i<4;++i) acc[m][n][i] = 0.0f;

    // ---------------- layer 2: B-frags are the lane's own pk registers ----------
    // dword i of step-s B-frag = pk[m][2s + (i>>1)][i&1]  (matches w2f repack)
    #pragma unroll
    for (int s = 0; s < 8; ++s) {
        const int c   = 12 + s;
        const int buf = c & 1;

        bf16x8 stg[4];
        if (s < 7) {
            const bf16x8* gn = chunkptr(c + 1);
            #pragma unroll
            for (int i=0;i<4;++i) stg[i] = gn[i*256 + tid];
        }

        i32x4 f0, f1;
        f0[0] = pk[0][2*s  ][0];  f0[1] = pk[0][2*s  ][1];
        f0[2] = pk[0][2*s+1][0];  f0[3] = pk[0][2*s+1][1];
        f1[0] = pk[1][2*s  ][0];  f1[1] = pk[1][2*s  ][1];
        f1[2] = pk[1][2*s+1][0];  f1[3] = pk[1][2*s+1][1];
        bf16x8 e0 = __builtin_bit_cast(bf16x8, f0);
        bf16x8 e1 = __builtin_bit_cast(bf16x8, f1);

        const bf16x8* sb = (const bf16x8*)stage[buf];
        #pragma unroll
        for (int t = 0; t < 16; ++t) {
            bf16x8 w = sb[t*64 + lane];
            acc[0][t] = __builtin_amdgcn_mfma_f32_16x16x32_bf16(w, e0, acc[0][t], 0,0,0);
            acc[1][t] = __builtin_amdgcn_mfma_f32_16x16x32_bf16(w, e1, acc[1][t], 0,0,0);
        }

        if (s < 7) {
            bf16x8* sd = (bf16x8*)stage[buf ^ 1];
            #pragma unroll
            for (int i=0;i<4;++i) sd[i*256 + tid] = stg[i];
            __syncthreads();
        }
    }

    // ---------------- epilogue 2: out = leaky(acc+b2), vectorized f32x4 stores ---
    #pragma unroll
    for (int t=0;t<16;++t) {
        const f32x4 bv = *(const f32x4*)(b2 + t*16 + lq*4);
        #pragma unroll
        for (int m=0;m<2;++m) {
            f32x4 o;
            #pragma unroll
            for (int r=0;r<4;++r) {
                float v = acc[m][t][r] + bv[r];
                o[r] = fmaxf(v, 0.01f*v);
            }
            const int row = rowblk + wv*32 + m*16 + l15;
            *(f32x4*)(out + (size_t)row*256 + t*16 + lq*4) = o;
        }
    }
}

extern "C" void kernel_launch(void* const* d_in, const int* in_sizes, int n_in,
                              void* d_out, int out_size, void* d_ws, size_t ws_size,
                              hipStream_t stream) {
    const float* xy   = (const float*)d_in[0];
    const float* tin  = (const float*)d_in[1];
    const float* w_sx = (const float*)d_in[2];
    const float* b_sx = (const float*)d_in[3];
    const float* w_cx = (const float*)d_in[4];
    const float* b_cx = (const float*)d_in[5];
    const float* w_sy = (const float*)d_in[6];
    const float* b_sy = (const float*)d_in[7];
    const float* w_cy = (const float*)d_in[8];
    const float* b_cy = (const float*)d_in[9];
    const float* w_t  = (const float*)d_in[10];
    const float* b_t  = (const float*)d_in[11];
    const float* w1   = (const float*)d_in[12];
    const float* b1   = (const float*)d_in[13];
    const float* w2   = (const float*)d_in[14];
    const float* b2   = (const float*)d_in[15];

    unsigned short* w1f = (unsigned short*)d_ws;        // 12*16*64*8 ushorts = 196608 B
    unsigned short* w2f = w1f + (size_t)W1_SLOTS * 8;   // 131072 B

    prep_weights<<<(W1_SLOTS + W2_SLOTS + 255)/256, 256, 0, stream>>>(w1, w2, w1f, w2f);
    courier_main<<<262144/128, 256, 0, stream>>>(xy, tin, w_sx,b_sx,w_cx,b_cx,
                                                 w_sy,b_sy,w_cy,b_cy,w_t,b_t,
                                                 w1f, b1, w2f, b2, (float*)d_out);
}